// Round 1
// 333.519 us; speedup vs baseline: 1.0380x; 1.0380x over previous
//
#include <hip/hip_runtime.h>
#include <math.h>

#define B 8
#define L 200
#define H 128
#define NH 4
#define DH 32

// nontemporal float4 load: tK/tV are read-once streams (327 MB/iter) --
// keep them from evicting the reused Kp/Vp panels out of the 4MB/XCD L2.
typedef float f4v __attribute__((ext_vector_type(4)));
__device__ __forceinline__ float4 ntld(const float4* p) {
    f4v v = __builtin_nontemporal_load((const f4v*)p);
    return make_float4(v[0], v[1], v[2], v[3]);
}

// ---------------------------------------------------------------------------
// Kernel 1: fused projections.
//   Qo  = queries @ Qw.T + Qb
//   Kpo = keys    @ Kw.T + Kb + abs_pos_K
//   Vpo = keys    @ Vw.T + Vb + abs_pos_V
// ---------------------------------------------------------------------------
__global__ __launch_bounds__(128) void proj_kernel(
    const float* __restrict__ queries, const float* __restrict__ keys,
    const float* __restrict__ apK, const float* __restrict__ apV,
    const float* __restrict__ Qw, const float* __restrict__ Qb,
    const float* __restrict__ Kw, const float* __restrict__ Kb,
    const float* __restrict__ Vw, const float* __restrict__ Vb,
    float* __restrict__ Qo, float* __restrict__ Kpo, float* __restrict__ Vpo)
{
    const int j    = threadIdx.x;        // output channel 0..127
    const int row0 = blockIdx.x * 8;     // first of 8 rows

    __shared__ float4 qrow[8 * 32];
    __shared__ float4 krow[8 * 32];

    const float4* q4 = (const float4*)queries + row0 * 32;
    const float4* k4 = (const float4*)keys    + row0 * 32;
    for (int idx = j; idx < 256; idx += 128) { qrow[idx] = q4[idx]; krow[idx] = k4[idx]; }
    __syncthreads();

    float accQ[8], accK[8], accV[8];
    const float qb = Qb[j], kb = Kb[j], vb = Vb[j];
    #pragma unroll
    for (int r = 0; r < 8; ++r) { accQ[r] = qb; accK[r] = kb; accV[r] = vb; }

    const float4* Qw4 = (const float4*)Qw + j * 32;
    const float4* Kw4 = (const float4*)Kw + j * 32;
    const float4* Vw4 = (const float4*)Vw + j * 32;

    #pragma unroll 2
    for (int k = 0; k < 32; ++k) {
        const float4 wq = Qw4[k];
        const float4 wk = Kw4[k];
        const float4 wv = Vw4[k];
        #pragma unroll
        for (int r = 0; r < 8; ++r) {
            const float4 x = qrow[r * 32 + k];
            accQ[r] = fmaf(wq.x, x.x, fmaf(wq.y, x.y, fmaf(wq.z, x.z, fmaf(wq.w, x.w, accQ[r]))));
            const float4 y = krow[r * 32 + k];
            accK[r] = fmaf(wk.x, y.x, fmaf(wk.y, y.y, fmaf(wk.z, y.z, fmaf(wk.w, y.w, accK[r]))));
            accV[r] = fmaf(wv.x, y.x, fmaf(wv.y, y.y, fmaf(wv.z, y.z, fmaf(wv.w, y.w, accV[r]))));
        }
    }

    #pragma unroll
    for (int r = 0; r < 8; ++r) {
        const int i = row0 + r;
        Qo [i * H + j] = accQ[r];
        Kpo[i * H + j] = accK[r] + apK[i * H + j];
        Vpo[i * H + j] = accV[r] + apV[i * H + j];
    }
}

// ---------------------------------------------------------------------------
// Kernel 2: attention. One block per (b, pair); each block handles TWO query
// rows l1 = pair and l2 = 199 - pair of the same batch b. Work per block is
// then near-constant ((l1+1) + (l2+1) = 201 phase-A rows), so all 800 blocks
// are (nearly) co-resident and finish together -- no dependence on dispatch
// order, no straggler tail.
//   thread t: c4 = t&31 (float4 channel, head c4>>3), part = t>>5 (0..15)
// CAUSAL SKIP: only m <= l rows are loaded. Fully time-masked rows skip
// phases A/B (softmax of all-NEG is exactly uniform 1/200 over all 200 rows).
// b = bid&7: under round-robin XCD dispatch each XCD sees exactly one b, so
// its L2 holds exactly that b's Kp/Vp panel (205 KB).
// ---------------------------------------------------------------------------

__device__ __forceinline__ void logits_phase(
    const float4 q, const int l,
    const float4* __restrict__ Kp4, const float4* __restrict__ tK4,
    float* __restrict__ S, const int c4, const int part, const int h)
{
    const int nsteps = (l + 16) >> 4;     // ceil((l+1)/16)
    for (int i0 = 0; i0 < nsteps; i0 += 4) {
        float4 kk[4], tt[4];
        int mm[4];
        #pragma unroll
        for (int u = 0; u < 4; ++u) {
            const int m = part + 16 * (i0 + u);
            mm[u] = m;
            if (m <= l) {
                kk[u] = Kp4[m * 32 + c4];
                tt[u] = ntld(&tK4[m * 32 + c4]);
            }
        }
        #pragma unroll
        for (int u = 0; u < 4; ++u) {
            const int m = mm[u];
            float v = 0.0f;
            if (m <= l) {
                v = fmaf(q.x, kk[u].x + tt[u].x,
                    fmaf(q.y, kk[u].y + tt[u].y,
                    fmaf(q.z, kk[u].z + tt[u].z,
                         q.w * (kk[u].w + tt[u].w))));
            }
            v += __shfl_down(v, 4, 8);
            v += __shfl_down(v, 2, 8);
            v += __shfl_down(v, 1, 8);
            if ((c4 & 7) == 0 && m <= l)
                S[h * L + m] = v * 0.17677669529663687f;  // 1/sqrt(32)
        }
    }
}

__device__ __forceinline__ float4 pv_phase(
    const int l, const bool rowmasked,
    const float4* __restrict__ Vp4, const float4* __restrict__ tV4,
    const float* __restrict__ S, const int c4, const int part, const int h)
{
    const int   nmV = rowmasked ? L : (l + 1);
    const float wU  = 1.0f / (float)L;
    float4 acc = make_float4(0.f, 0.f, 0.f, 0.f);
    const int nstepsV = (nmV + 15) >> 4;
    for (int i0 = 0; i0 < nstepsV; i0 += 4) {
        float4 vv[4], tt[4];
        int mm[4];
        #pragma unroll
        for (int u = 0; u < 4; ++u) {
            const int m = part + 16 * (i0 + u);
            mm[u] = m;
            if (m < nmV) {
                vv[u] = Vp4[m * 32 + c4];
                tt[u] = ntld(&tV4[m * 32 + c4]);
            }
        }
        #pragma unroll
        for (int u = 0; u < 4; ++u) {
            const int m = mm[u];
            if (m < nmV) {
                const float w = rowmasked ? wU : S[h * L + m];
                acc.x = fmaf(w, vv[u].x + tt[u].x, acc.x);
                acc.y = fmaf(w, vv[u].y + tt[u].y, acc.y);
                acc.z = fmaf(w, vv[u].z + tt[u].z, acc.z);
                acc.w = fmaf(w, vv[u].w + tt[u].w, acc.w);
            }
        }
    }
    return acc;
}

__global__ __launch_bounds__(512) void attn_kernel(
    const float* __restrict__ Qo, const float* __restrict__ Kp,
    const float* __restrict__ Vp,
    const float* __restrict__ tK, const float* __restrict__ tV,
    const int* __restrict__ tmask, float* __restrict__ out)
{
    const int bid = blockIdx.x;         // 0..799
    const int b   = bid & 7;
    const int l1  = bid >> 3;           // 0..99
    const int l2  = L - 1 - l1;         // 199..100
    const int bl1 = b * L + l1;
    const int bl2 = b * L + l2;
    const int t   = threadIdx.x;
    const int c4   = t & 31;            // float4 channel index
    const int part = t >> 5;            // 0..15
    const int h    = c4 >> 3;           // head for this channel group

    __shared__ float  S1[NH * L];       // logits/weights for l1
    __shared__ float  S2[NH * L];       // logits/weights for l2
    __shared__ float4 P1[32 * 17];      // phase-C partials (stride 17)
    __shared__ float4 P2[32 * 17];

    const bool rm1 = (tmask[bl1] != 0);
    const bool rm2 = (tmask[bl2] != 0);

    const float4* Kp4  = (const float4*)Kp + (size_t)b * L * 32;
    const float4* Vp4  = (const float4*)Vp + (size_t)b * L * 32;
    const float4* tK41 = (const float4*)tK + (size_t)bl1 * L * 32;
    const float4* tK42 = (const float4*)tK + (size_t)bl2 * L * 32;
    const float4* tV41 = (const float4*)tV + (size_t)bl1 * L * 32;
    const float4* tV42 = (const float4*)tV + (size_t)bl2 * L * 32;

    // ---- Phase A: logits for both rows (skipped per-row if fully masked) --
    if (!rm2) {
        const float4 q2 = ((const float4*)Qo)[bl2 * 32 + c4];
        logits_phase(q2, l2, Kp4, tK42, S2, c4, part, h);
    }
    if (!rm1) {
        const float4 q1 = ((const float4*)Qo)[bl1 * 32 + c4];
        logits_phase(q1, l1, Kp4, tK41, S1, c4, part, h);
    }
    __syncthreads();

    // ---- Phase B: softmax. waves 0..3 -> heads of l1, waves 4..7 -> l2 ----
    {
        const int  half = t >> 8;       // 0: l1, 1: l2
        const int  hw   = (t >> 6) & 3; // head
        const int  lane = t & 63;
        const bool rm   = half ? rm2 : rm1;
        if (!rm) {
            const int l  = half ? l2 : l1;
            float*    Sx = half ? S2 : S1;
            float mx = -INFINITY;
            for (int m = lane; m <= l; m += 64) mx = fmaxf(mx, Sx[hw * L + m]);
            #pragma unroll
            for (int off = 32; off; off >>= 1) mx = fmaxf(mx, __shfl_xor(mx, off));
            float s = 0.0f;
            for (int m = lane; m <= l; m += 64) s += __expf(Sx[hw * L + m] - mx);
            #pragma unroll
            for (int off = 32; off; off >>= 1) s += __shfl_xor(s, off);
            const float inv = 1.0f / s;
            for (int m = lane; m <= l; m += 64)
                Sx[hw * L + m] = __expf(Sx[hw * L + m] - mx) * inv;
        }
    }
    __syncthreads();

    // ---- Phase C: out = sum_m w * (V' + tV) for both rows ----
    const float4 a2 = pv_phase(l2, rm2, Vp4, tV42, S2, c4, part, h);
    const float4 a1 = pv_phase(l1, rm1, Vp4, tV41, S1, c4, part, h);
    P1[c4 * 17 + part] = a1;
    P2[c4 * 17 + part] = a2;
    __syncthreads();

    if (t < 64) {
        const int half = t >> 5;        // 0: l1, 1: l2
        const int ch   = t & 31;
        const float4* Pp = half ? P2 : P1;
        float4 tot = make_float4(0.f, 0.f, 0.f, 0.f);
        #pragma unroll
        for (int p = 0; p < 16; ++p) {
            const float4 a = Pp[ch * 17 + p];
            tot.x += a.x; tot.y += a.y; tot.z += a.z; tot.w += a.w;
        }
        ((float4*)out)[(half ? bl2 : bl1) * 32 + ch] = tot;
    }
}

extern "C" void kernel_launch(void* const* d_in, const int* in_sizes, int n_in,
                              void* d_out, int out_size, void* d_ws, size_t ws_size,
                              hipStream_t stream) {
    const float* queries = (const float*)d_in[0];
    const float* keys    = (const float*)d_in[1];
    const int*   tmask   = (const int*)d_in[2];
    // d_in[3] = attn_mask: deterministic causal (m > l), recomputed in-kernel.
    const float* tK   = (const float*)d_in[4];
    const float* tV   = (const float*)d_in[5];
    const float* apK  = (const float*)d_in[6];
    const float* apV  = (const float*)d_in[7];
    const float* Qw   = (const float*)d_in[8];
    const float* Qb   = (const float*)d_in[9];
    const float* Kw   = (const float*)d_in[10];
    const float* Kb   = (const float*)d_in[11];
    const float* Vw   = (const float*)d_in[12];
    const float* Vb   = (const float*)d_in[13];
    float* out = (float*)d_out;

    // workspace: Q (819.2KB) | K' (819.2KB) | V' (819.2KB)
    float* Qo  = (float*)d_ws;
    float* Kpo = Qo  + (size_t)B * L * H;
    float* Vpo = Kpo + (size_t)B * L * H;

    proj_kernel<<<(B * L) / 8, 128, 0, stream>>>(
        queries, keys, apK, apV, Qw, Qb, Kw, Kb, Vw, Vb, Qo, Kpo, Vpo);

    attn_kernel<<<(B * L) / 2, 512, 0, stream>>>(Qo, Kpo, Vpo, tK, tV, tmask, out);
}